// Round 1
// baseline (306.854 us; speedup 1.0000x reference)
//
#include <hip/hip_runtime.h>

// 9x9 box-sum (R=4) over each (b,c) 512x512 fp32 plane, zero-padded.
// Separable: horizontal 9-tap into LDS, vertical 9-tap sliding window in regs.

#define RAD   4
#define KK    9
#define TILE  64
#define HALOW (TILE + 2 * RAD)   // 72
#define W     512

__global__ __launch_bounds__(256) void boxfilter9(const float* __restrict__ in,
                                                  float* __restrict__ out) {
    __shared__ float s_in[HALOW][HALOW + 1];   // 72 x 73 (pad to keep rows offset)
    __shared__ float s_h[HALOW][TILE];         // 72 x 64 horizontal sums

    const int img = blockIdx.z;                 // b*16 + c, 0..127
    const float* __restrict__ inp = in + (size_t)img * W * W;
    float* __restrict__ outp = out + (size_t)img * W * W;

    const int x0 = blockIdx.x * TILE;
    const int y0 = blockIdx.y * TILE;
    const int tid = threadIdx.x;

    // ---- Stage 72x72 halo tile into LDS (zero pad at image edges) ----
    for (int idx = tid; idx < HALOW * HALOW; idx += 256) {
        const int r = idx / HALOW;
        const int c = idx - r * HALOW;
        const int gy = y0 + r - RAD;
        const int gx = x0 + c - RAD;
        float v = 0.0f;
        if (gy >= 0 && gy < W && gx >= 0 && gx < W)
            v = inp[gy * W + gx];
        s_in[r][c] = v;
    }
    __syncthreads();

    // ---- Horizontal 9-tap: s_h[r][c] = sum_{d=0..8} s_in[r][c+d] ----
    // wave-uniform row: lanes = columns (conflict-free, stride-1)
    {
        const int c = tid & (TILE - 1);
        const int rstart = tid >> 6;            // 0..3
        for (int r = rstart; r < HALOW; r += 4) {
            float s = 0.0f;
            #pragma unroll
            for (int d = 0; d < KK; ++d) s += s_in[r][c + d];
            s_h[r][c] = s;
        }
    }
    __syncthreads();

    // ---- Vertical 9-tap with register sliding window ----
    // thread handles one column, 16 consecutive output rows
    {
        const int c = tid & (TILE - 1);
        const int r0 = (tid >> 6) * 16;         // 0,16,32,48
        float s = 0.0f;
        #pragma unroll
        for (int d = 0; d < KK - 1; ++d) s += s_h[r0 + d][c];
        #pragma unroll
        for (int i = 0; i < 16; ++i) {
            s += s_h[r0 + i + KK - 1][c];
            outp[(y0 + r0 + i) * W + (x0 + c)] = s;
            s -= s_h[r0 + i][c];
        }
    }
}

extern "C" void kernel_launch(void* const* d_in, const int* in_sizes, int n_in,
                              void* d_out, int out_size, void* d_ws, size_t ws_size,
                              hipStream_t stream) {
    const float* x = (const float*)d_in[0];
    float* y = (float*)d_out;
    dim3 grid(W / TILE, W / TILE, 8 * 16);   // 8 x 8 x 128
    dim3 block(256);
    boxfilter9<<<grid, block, 0, stream>>>(x, y);
}

// Round 2
// 240.214 us; speedup vs baseline: 1.2774x; 1.2774x over previous
//
#include <hip/hip_runtime.h>

// 9x9 box-sum (R=4), zero-padded, over 128 fp32 planes of 512x512.
// Pure streaming: no LDS, no barriers. Thread = 4 cols x 32 rows.
// Horizontal 9-sum in registers from 3 overlapping float4 loads (L1-merged),
// vertical 9-sum via register ring + running sum.

#define W   512
#define RR  32          // output rows per thread strip
#define NSTRIP (W / RR) // 16

__device__ __forceinline__ float4 ld4(const float* p) { return *(const float4*)p; }
__device__ __forceinline__ float4 add4(float4 a, float4 b) {
    return make_float4(a.x + b.x, a.y + b.y, a.z + b.z, a.w + b.w);
}
__device__ __forceinline__ float4 sub4(float4 a, float4 b) {
    return make_float4(a.x - b.x, a.y - b.y, a.z - b.z, a.w - b.w);
}

__global__ __launch_bounds__(256, 4) void boxfilter9(const float* __restrict__ in,
                                                     float* __restrict__ out) {
    const int t     = threadIdx.x;
    const int unit  = blockIdx.x * 2 + (t >> 7);   // img*NSTRIP + strip  (wave-uniform)
    const int img   = unit >> 4;                   // /16
    const int strip = unit & (NSTRIP - 1);
    const int cg    = t & 127;
    const int c0    = cg << 2;                     // output col base (multiple of 4)

    const float* __restrict__ inp  = in  + (size_t)img * W * W;
    float* __restrict__       outp = out + (size_t)img * W * W;
    const int  y0    = strip * RR;
    const bool has_l = (c0 >= 4);
    const bool has_r = (c0 + 4 < W);

    // horizontal 9-sum of input row y for cols c0..c0+3 (zero pad outside image)
    auto compute_h = [&](int y) -> float4 {
        float4 h;
        if ((unsigned)y < W) {                      // wave-uniform branch
            const float* row = inp + y * W;
            float4 a = has_l ? ld4(row + c0 - 4) : make_float4(0, 0, 0, 0);
            float4 b = ld4(row + c0);
            float4 c = has_r ? ld4(row + c0 + 4) : make_float4(0, 0, 0, 0);
            float s0 = ((a.x + a.y) + (a.z + a.w)) +
                       (((b.x + b.y) + (b.z + b.w)) + c.x);
            h.x = s0;
            h.y = s0  - a.x + c.y;
            h.z = h.y - a.y + c.z;
            h.w = h.z - a.z + c.w;
        } else {
            h = make_float4(0, 0, 0, 0);
        }
        return h;
    };

    // init: ring[0..7] = h(y0-4 .. y0+3), vsum = their sum (8 rows of the window)
    float4 ring[9];
    float4 vsum = make_float4(0, 0, 0, 0);
    #pragma unroll
    for (int k = 0; k < 8; ++k) {
        ring[k] = compute_h(y0 - 4 + k);
        vsum = add4(vsum, ring[k]);
    }

    // 32 output rows; full unroll -> static ring indices, deep load pipelining
    #pragma unroll
    for (int i = 0; i < RR; ++i) {
        float4 hn = compute_h(y0 + 4 + i);         // bottom row of window
        float4 o  = add4(vsum, hn);                // 9-row total
        *(float4*)(outp + (size_t)(y0 + i) * W + c0) = o;
        vsum = sub4(o, ring[i % 9]);               // drop top row for next step
        ring[(i + 8) % 9] = hn;
    }
}

extern "C" void kernel_launch(void* const* d_in, const int* in_sizes, int n_in,
                              void* d_out, int out_size, void* d_ws, size_t ws_size,
                              hipStream_t stream) {
    const float* x = (const float*)d_in[0];
    float* y = (float*)d_out;
    // 128 images x 16 strips = 2048 units, 2 units per 256-thread block
    dim3 grid(128 * NSTRIP / 2);
    dim3 block(256);
    boxfilter9<<<grid, block, 0, stream>>>(x, y);
}